// Round 11
// baseline (959.427 us; speedup 1.0000x reference)
//
#include <hip/hip_runtime.h>

// RGCN node classification (matmul-first; round-8 CSR + XCD-col-sliced pulls):
//   layer0: h  = relu(b0 + sum_r agg_r(embed))            [sliced pull]
//   layer1: t  = h @ vstack-cols(w1)  (N=1024, bf16)      [MFMA GEMM]
//           h2 = relu(b1 + sum_r agg_r(t[:, r*256:..]))   [sliced pull]
//   layer2: q  = h2 @ vstack-cols(w_out) (N=256, bf16)    [MFMA GEMM]
//           out= b_out + sum_r agg_r(q[:, r*64:..])       [pull, 4 edge slots]
// Sliced pull: slice = blockIdx&7 (~XCD under round-robin) owns a 64B column
// slice -> per-XCD gather working set 3.2MB, L2-resident. Each edge = one
// 64B line request (4 lanes x 16B), 16 edges in flight per wave.

typedef unsigned short ushort_t;
using f32x4  = __attribute__((ext_vector_type(4))) float;
using short8 = __attribute__((ext_vector_type(8))) short;

__device__ inline float bf2f(unsigned s) { return __uint_as_float(s << 16); }
__device__ inline unsigned short f2bf(float f) {
  unsigned u = __float_as_uint(f);
  u += 0x7FFF + ((u >> 16) & 1);  // round-to-nearest-even
  return (unsigned short)(u >> 16);
}
__device__ inline void u4tof8(const uint4 v, float f[8]) {
  f[0] = bf2f(v.x & 0xffffu); f[1] = bf2f(v.x >> 16);
  f[2] = bf2f(v.y & 0xffffu); f[3] = bf2f(v.y >> 16);
  f[4] = bf2f(v.z & 0xffffu); f[5] = bf2f(v.z >> 16);
  f[6] = bf2f(v.w & 0xffffu); f[7] = bf2f(v.w >> 16);
}

// ---------------- CSR build (round-8 rank trick) ----------------
// Pass 1: rank[g] = atomicAdd(cnt[r][dst[g]], 1). After this, cnt = degrees.
__global__ void rank_k(const int* __restrict__ dst, int E, int Nn,
                       int* __restrict__ cnt, int* __restrict__ rank) {
  int base = (blockIdx.x * blockDim.x + threadIdx.x) * 8;
  int r = blockIdx.y;
  if (base >= E) return;
  const int* dr = dst + (size_t)r * E;
  int* cr = cnt + (size_t)r * Nn;
  int* rk = rank + (size_t)r * E;
  if (base + 7 < E) {
    const int4 a = *reinterpret_cast<const int4*>(dr + base);
    const int4 b = *reinterpret_cast<const int4*>(dr + base + 4);
    int4 ra, rb;
    ra.x = atomicAdd(&cr[a.x], 1); ra.y = atomicAdd(&cr[a.y], 1);
    ra.z = atomicAdd(&cr[a.z], 1); ra.w = atomicAdd(&cr[a.w], 1);
    rb.x = atomicAdd(&cr[b.x], 1); rb.y = atomicAdd(&cr[b.y], 1);
    rb.z = atomicAdd(&cr[b.z], 1); rb.w = atomicAdd(&cr[b.w], 1);
    *reinterpret_cast<int4*>(rk + base) = ra;
    *reinterpret_cast<int4*>(rk + base + 4) = rb;
  } else {
    for (int j = 0; j < 8 && base + j < E; j++)
      rk[base + j] = atomicAdd(&cr[dr[base + j]], 1);
  }
}

// Phase A: per-block (1024 elems) exclusive scan of cnt -> rowptr, block sums.
__global__ __launch_bounds__(1024) void scanA_k(const int* __restrict__ degcnt, int M,
                                                int* __restrict__ rowptr,
                                                int* __restrict__ blocksum) {
  __shared__ int sm[1024];
  int t = threadIdx.x;
  int g = blockIdx.x * 1024 + t;
  int v = (g < M) ? degcnt[g] : 0;
  sm[t] = v;
  __syncthreads();
  for (int off = 1; off < 1024; off <<= 1) {
    int u = (t >= off) ? sm[t - off] : 0;
    __syncthreads();
    sm[t] += u;
    __syncthreads();
  }
  if (g < M) rowptr[g] = sm[t] - v;
  if (t == 1023) blocksum[blockIdx.x] = sm[1023];
}

// Phase B: one block scans the block sums (exclusive, in place). nb <= 1024.
__global__ __launch_bounds__(1024) void scanB_k(int* __restrict__ blocksum, int nb) {
  __shared__ int sm[1024];
  int t = threadIdx.x;
  int v = (t < nb) ? blocksum[t] : 0;
  sm[t] = v;
  __syncthreads();
  for (int off = 1; off < 1024; off <<= 1) {
    int u = (t >= off) ? sm[t - off] : 0;
    __syncthreads();
    sm[t] += u;
    __syncthreads();
  }
  if (t < nb) blocksum[t] = sm[t] - v;
}

// Phase C: add block offset; emit final rowptr and invdeg.
__global__ __launch_bounds__(1024) void scanC_k(const int* __restrict__ degcnt, int M,
                                                const int* __restrict__ blocksum,
                                                int* __restrict__ rowptr,
                                                float* __restrict__ invdeg) {
  int g = blockIdx.x * 1024 + threadIdx.x;
  if (g < M) {
    int val = rowptr[g] + blocksum[blockIdx.x];
    int dd = degcnt[g];
    rowptr[g] = val;
    invdeg[g] = 1.0f / (float)(dd > 0 ? dd : 1);
    if (g == M - 1) rowptr[M] = val + dd;
  }
}

// Pass 2: eidx[rowptr[r][dst] + rank] = src. NO atomics.
__global__ void fill_k(const int* __restrict__ src, const int* __restrict__ dst,
                       const int* __restrict__ rank,
                       const int* __restrict__ rowptr, int E, int Nn,
                       int* __restrict__ eidx) {
  int base = (blockIdx.x * blockDim.x + threadIdx.x) * 8;
  int r = blockIdx.y;
  if (base >= E) return;
  const int* dr = dst + (size_t)r * E;
  const int* sr = src + (size_t)r * E;
  const int* rk = rank + (size_t)r * E;
  const int* rp = rowptr + (size_t)r * Nn;
  if (base + 7 < E) {
    const int4 d0 = *reinterpret_cast<const int4*>(dr + base);
    const int4 d1 = *reinterpret_cast<const int4*>(dr + base + 4);
    const int4 s0 = *reinterpret_cast<const int4*>(sr + base);
    const int4 s1 = *reinterpret_cast<const int4*>(sr + base + 4);
    const int4 k0 = *reinterpret_cast<const int4*>(rk + base);
    const int4 k1 = *reinterpret_cast<const int4*>(rk + base + 4);
    eidx[rp[d0.x] + k0.x] = s0.x;
    eidx[rp[d0.y] + k0.y] = s0.y;
    eidx[rp[d0.z] + k0.z] = s0.z;
    eidx[rp[d0.w] + k0.w] = s0.w;
    eidx[rp[d1.x] + k1.x] = s1.x;
    eidx[rp[d1.y] + k1.y] = s1.y;
    eidx[rp[d1.z] + k1.z] = s1.z;
    eidx[rp[d1.w] + k1.w] = s1.w;
  } else {
    for (int j = 0; j < 8 && base + j < E; j++)
      eidx[rp[dr[base + j]] + rk[base + j]] = sr[base + j];
  }
}

// ---------------- prep: f32 -> bf16, weight transpose ----------------
__global__ void f2bf_vec_k(const float* __restrict__ in, ushort_t* __restrict__ out,
                           long n4) {
  long i = (long)blockIdx.x * blockDim.x + threadIdx.x;
  if (i < n4) {
    float4 v = *reinterpret_cast<const float4*>(in + i * 4);
    ushort4 o; o.x = f2bf(v.x); o.y = f2bf(v.y); o.z = f2bf(v.z); o.w = f2bf(v.w);
    *reinterpret_cast<ushort4*>(out + i * 4) = o;
  }
}

// Bt[j][k] = (bf16) w[r][k][c] with j = r*Nd + c.
__global__ void wtrans_k(const float* __restrict__ w, ushort_t* __restrict__ wt,
                         int K, int Nd, int total) {
  int tid = blockIdx.x * blockDim.x + threadIdx.x;
  if (tid < total) {
    int k = tid % K;
    int j = tid / K;
    int c = j % Nd;
    int r = j / Nd;
    wt[(size_t)j * K + k] = f2bf(w[((size_t)r * K + k) * Nd + c]);
  }
}

// ---------- XCD-col-sliced pull, 256-col output, bias+relu, bf16 out --------
// grid.x = ceil(Nn/4)*8; slice = bid&7 (XCD affinity), 4 nodes/block (1/wave).
// lane: slot = lane>>2 (16 edge slots), cl = lane&3 (16B column sub-slice).
// Per edge: 4 lanes x uint4 = one aligned 64B line from this slice's window.
__global__ __launch_bounds__(256) void pull_slice256_k(
    const ushort_t* __restrict__ x, int xpitch, int rsub,
    const int* __restrict__ eidx,
    const int* __restrict__ rowptr, const float* __restrict__ invdeg,
    int R, int Nn, ushort_t* __restrict__ out, const float* __restrict__ bias) {
  int slice = blockIdx.x & 7;
  int node = ((blockIdx.x >> 3) << 2) + (threadIdx.x >> 6);
  if (node >= Nn) return;
  int lane = threadIdx.x & 63;
  int slot = lane >> 2;
  int cl = lane & 3;
  int colOff = slice * 32 + cl * 8;
  float s[8] = {};
  for (int r = 0; r < R; r++) {
    const int* rp = rowptr + (size_t)r * Nn;   // flat; rp[node+1] valid at boundary
    int sb = rp[node], e = rp[node + 1];
    size_t rb = (size_t)(r * rsub + colOff);
    float p[8] = {};
    for (int i = sb + slot; i < e; i += 16) {
      const uint4 v = *reinterpret_cast<const uint4*>(x + (size_t)eidx[i] * xpitch + rb);
      float a[8];
      u4tof8(v, a);
#pragma unroll
      for (int j = 0; j < 8; j++) p[j] += a[j];
    }
    float w = invdeg[(size_t)r * Nn + node];
#pragma unroll
    for (int j = 0; j < 8; j++) s[j] += p[j] * w;
  }
  // reduce over 16 slots (lane bits 2..5)
#pragma unroll
  for (int m = 4; m <= 32; m <<= 1)
#pragma unroll
    for (int j = 0; j < 8; j++) s[j] += __shfl_xor(s[j], m, 64);
  if (slot == 0) {
    const float4 ba = *reinterpret_cast<const float4*>(bias + colOff);
    const float4 bb = *reinterpret_cast<const float4*>(bias + colOff + 4);
    s[0] += ba.x; s[1] += ba.y; s[2] += ba.z; s[3] += ba.w;
    s[4] += bb.x; s[5] += bb.y; s[6] += bb.z; s[7] += bb.w;
    short8 ov;
#pragma unroll
    for (int j = 0; j < 8; j++) ov[j] = (short)f2bf(fmaxf(s[j], 0.f));
    *reinterpret_cast<short8*>(out + ((size_t)node << 8) + colOff) = ov;
  }
}

// ---------------- output pull, 64 cols: 4 edge slots x 16 lanes x uint2 ------
__global__ __launch_bounds__(256) void pull_out64_k(
    const ushort_t* __restrict__ q, int qpitch,
    const int* __restrict__ eidx,
    const int* __restrict__ rowptr, const float* __restrict__ invdeg,
    int R, int Nn, float* __restrict__ out, const float* __restrict__ bias) {
  int node = (blockIdx.x * blockDim.x + threadIdx.x) >> 6;
  if (node >= Nn) return;
  int lane = threadIdx.x & 63;
  int es = lane >> 4;           // edge slot 0..3
  int c4 = (lane & 15) << 2;    // 4 cols per lane (uint2 = 4 bf16)
  float s[4] = {};
  for (int r = 0; r < R; r++) {
    const int* rp = rowptr + (size_t)r * Nn;
    int sb = rp[node], e = rp[node + 1];
    size_t rb = (size_t)((r << 6) + c4);
    float p[4] = {};
    for (int i = sb + es; i < e; i += 4) {
      const uint2 v = *reinterpret_cast<const uint2*>(q + (size_t)eidx[i] * qpitch + rb);
      p[0] += bf2f(v.x & 0xffffu); p[1] += bf2f(v.x >> 16);
      p[2] += bf2f(v.y & 0xffffu); p[3] += bf2f(v.y >> 16);
    }
    float w = invdeg[(size_t)r * Nn + node];
#pragma unroll
    for (int j = 0; j < 4; j++) s[j] += p[j] * w;
  }
#pragma unroll
  for (int j = 0; j < 4; j++) {
    s[j] += __shfl_xor(s[j], 16, 64);
    s[j] += __shfl_xor(s[j], 32, 64);
  }
  if (es == 0) {
    const float4 bv = *reinterpret_cast<const float4*>(bias + c4);
    float4 o;
    o.x = s[0] + bv.x; o.y = s[1] + bv.y; o.z = s[2] + bv.z; o.w = s[3] + bv.w;
    *reinterpret_cast<float4*>(out + ((size_t)node << 6) + c4) = o;
  }
}

// ---------------- bf16 MFMA GEMM (no bias/relu, bf16 store) ----------------
template <int FN>
__global__ __launch_bounds__(256) void gemm_mfma_k(
    const ushort_t* __restrict__ A, const ushort_t* __restrict__ Bt,
    ushort_t* __restrict__ Cp, int M, int K, int Nd) {
  __shared__ ushort_t Atile[128][72];
  const int tid = threadIdx.x;
  const int lane = tid & 63;
  const int wid = tid >> 6;
  const int wr = wid >> 1;
  const int wc = wid & 1;
  const int rowBase = blockIdx.y * 128;
  const int colBase = blockIdx.x * (FN * 32);
  const int l15 = lane & 15;
  const int g = lane >> 4;

  f32x4 acc[4][FN] = {};

  const int srow = tid >> 3;
  const int schunk = tid & 7;

  for (int k0 = 0; k0 < K; k0 += 64) {
#pragma unroll
    for (int i = 0; i < 4; i++) {
      int row = srow + i * 32;
      int grow = rowBase + row;
      if (grow >= M) grow = M - 1;  // clamp: affects only unstored C rows
      short8 v = *reinterpret_cast<const short8*>(A + (size_t)grow * K + k0 + schunk * 8);
      *reinterpret_cast<short8*>(&Atile[row][schunk * 8]) = v;
    }
    __syncthreads();
#pragma unroll
    for (int kk = 0; kk < 2; kk++) {
      short8 a[4], b[FN];
#pragma unroll
      for (int m = 0; m < 4; m++)
        a[m] = *reinterpret_cast<const short8*>(&Atile[wr * 64 + m * 16 + l15][kk * 32 + g * 8]);
#pragma unroll
      for (int n = 0; n < FN; n++) {
        int col = colBase + wc * (FN * 16) + n * 16 + l15;
        b[n] = *reinterpret_cast<const short8*>(Bt + (size_t)col * K + k0 + kk * 32 + g * 8);
      }
#pragma unroll
      for (int m = 0; m < 4; m++)
#pragma unroll
        for (int n = 0; n < FN; n++)
          acc[m][n] = __builtin_amdgcn_mfma_f32_16x16x32_bf16(a[m], b[n], acc[m][n], 0, 0, 0);
    }
    __syncthreads();
  }

  // C/D layout: col=lane&15, row=(lane>>4)*4+reg  [guide §3, m89-verified]
#pragma unroll
  for (int n = 0; n < FN; n++) {
    int col = colBase + wc * (FN * 16) + n * 16 + l15;
#pragma unroll
    for (int m = 0; m < 4; m++) {
      int row0 = rowBase + wr * 64 + m * 16 + g * 4;
#pragma unroll
      for (int j = 0; j < 4; j++) {
        int row = row0 + j;
        if (row < M) Cp[(size_t)row * Nd + col] = f2bf(acc[m][n][j]);
      }
    }
  }
}

extern "C" void kernel_launch(void* const* d_in, const int* in_sizes, int n_in,
                              void* d_out, int out_size, void* d_ws, size_t ws_size,
                              hipStream_t stream) {
  const float* embed = (const float*)d_in[0];
  const int* src     = (const int*)d_in[1];
  const int* dst     = (const int*)d_in[2];
  const float* b0    = (const float*)d_in[3];
  const float* w1    = (const float*)d_in[4];
  const float* b1    = (const float*)d_in[5];
  const float* w_out = (const float*)d_in[6];
  const float* b_out = (const float*)d_in[7];
  float* out = (float*)d_out;

  const int D = in_sizes[3];            // 256
  const int C = in_sizes[7];            // 64
  const int N = in_sizes[0] / D;        // 50000
  const int R = in_sizes[4] / (D * D);  // 4
  const int E = in_sizes[1] / R;        // 400000
  const int M = R * N;                  // scan length
  const int N1 = R * D;                 // 1024 gemm1 out cols
  const int N2 = R * C;                 // 256  gemm2 out cols

  char* w = (char*)d_ws;
  size_t off = 0;
  auto carve = [&](size_t bytes) -> void* {
    void* p = w + off;
    off += (bytes + 255) & ~(size_t)255;
    return p;
  };
  ushort_t* ebf  = (ushort_t*)carve((size_t)N * D * 2);       // 25.6 MB (reused as h2)
  ushort_t* h    = (ushort_t*)carve((size_t)N * D * 2);       // 25.6 MB
  ushort_t* t    = (ushort_t*)carve((size_t)N * N1 * 2);      // 102.4 MB (reused as q; rank aliases head)
  ushort_t* w1t  = (ushort_t*)carve((size_t)N1 * D * 2);      // 0.5 MB
  ushort_t* wot  = (ushort_t*)carve((size_t)N2 * D * 2);      // 0.13 MB
  float* invdeg  = (float*)carve((size_t)M * 4);
  int* rowptr    = (int*)carve(((size_t)M + 1) * 4);
  int* degcnt    = (int*)carve((size_t)M * 4);
  int* eidx      = (int*)carve((size_t)R * E * 4);
  int* blocksum  = (int*)carve(1024 * 4);
  ushort_t* h2 = ebf;   // ebf dead after layer-0 pull
  ushort_t* q  = t;     // t dead after layer-1 pull
  int* rank = (int*)t;  // t-space unused until gemm1; rank dead after fill_k
  (void)n_in; (void)out_size; (void)ws_size;

  // --- CSR build: rank pass (atomic, leaves degrees) -> scan -> atomic-free fill ---
  hipMemsetAsync(degcnt, 0, (size_t)M * 4, stream);
  dim3 egrid((E + 2047) / 2048, R);
  rank_k<<<egrid, 256, 0, stream>>>(dst, E, N, degcnt, rank);
  int nblkScan = (M + 1023) / 1024;     // 196 <= 1024
  scanA_k<<<nblkScan, 1024, 0, stream>>>(degcnt, M, rowptr, blocksum);
  scanB_k<<<1, 1024, 0, stream>>>(blocksum, nblkScan);
  scanC_k<<<nblkScan, 1024, 0, stream>>>(degcnt, M, blocksum, rowptr, invdeg);
  fill_k<<<egrid, 256, 0, stream>>>(src, dst, rank, rowptr, E, N, eidx);

  // --- prep: embed->bf16, weights -> [outcol][k] bf16 ---
  long n4 = (long)N * D / 4;
  f2bf_vec_k<<<(int)((n4 + 255) / 256), 256, 0, stream>>>(embed, ebf, n4);
  wtrans_k<<<(N1 * D + 255) / 256, 256, 0, stream>>>(w1, w1t, D, D, N1 * D);
  wtrans_k<<<(N2 * D + 255) / 256, 256, 0, stream>>>(w_out, wot, D, C, N2 * D);

  const int sliceBlocks = ((N + 3) / 4) * 8;               // 4 nodes/block x 8 slices
  const int pullBlocks1 = (N * 64 + 255) / 256;            // 1 node per wave

  // --- layer 0: h = relu(b0 + sum_r agg_r(embed)) ---
  pull_slice256_k<<<sliceBlocks, 256, 0, stream>>>(ebf, D, 0, eidx, rowptr, invdeg,
                                                   R, N, h, b0);

  // --- layer 1: t = h @ w1cat; h2 = relu(b1 + sum_r agg_r(t[:,r*256:])) ---
  {
    dim3 grid(N1 / 128, (N + 127) / 128);
    gemm_mfma_k<4><<<grid, 256, 0, stream>>>(h, w1t, t, N, D, N1);
  }
  pull_slice256_k<<<sliceBlocks, 256, 0, stream>>>(t, N1, D, eidx, rowptr, invdeg,
                                                   R, N, h2, b1);

  // --- layer 2: q = h2 @ wocat; out = b_out + sum_r agg_r(q[:,r*64:]) ---
  {
    dim3 grid(N2 / 128, (N + 127) / 128);
    gemm_mfma_k<4><<<grid, 256, 0, stream>>>(h2, wot, q, N, D, N2);
  }
  pull_out64_k<<<pullBlocks1, 256, 0, stream>>>(q, N2, eidx, rowptr, invdeg,
                                                R, N, out, b_out);
}

// Round 12
// 517.405 us; speedup vs baseline: 1.8543x; 1.8543x over previous
//
#include <hip/hip_runtime.h>

// RGCN node classification (round-8 structure + XCD-chunked GEMM swizzle):
//   layer0: h  = relu(b0 + sum_r agg_r(embed))            [pull, 2 nodes/wave]
//   layer1: t  = h @ vstack-cols(w1)  (N=1024, bf16)      [MFMA GEMM, T1 swizzle]
//           h2 = relu(b1 + sum_r agg_r(t[:, r*256:..]))   [pull, 2 nodes/wave]
//   layer2: q  = h2 @ vstack-cols(w_out) (N=256, bf16)    [MFMA GEMM, T1 swizzle]
//           out= b_out + sum_r agg_r(q[:, r*64:..])       [pull, 4 edge slots]
// CSR per call via rank trick (pass1 atomicAdd returns rank + leaves degrees;
// pass2 scatter atomic-free). Pulls: measured L3-gather plateau ~3.6TB/s —
// left at round-8 form (2 attempts to beat it failed). GEMMs get bijective
// XCD-chunked blockIdx swizzle so col-tiles sharing an A row-tile co-locate
// on one XCD's L2 (cuts the 8x A re-fetch).

typedef unsigned short ushort_t;
using f32x4  = __attribute__((ext_vector_type(4))) float;
using short8 = __attribute__((ext_vector_type(8))) short;

__device__ inline float bf2f(unsigned s) { return __uint_as_float(s << 16); }
__device__ inline unsigned short f2bf(float f) {
  unsigned u = __float_as_uint(f);
  u += 0x7FFF + ((u >> 16) & 1);  // round-to-nearest-even
  return (unsigned short)(u >> 16);
}
__device__ inline void u4tof8(const uint4 v, float f[8]) {
  f[0] = bf2f(v.x & 0xffffu); f[1] = bf2f(v.x >> 16);
  f[2] = bf2f(v.y & 0xffffu); f[3] = bf2f(v.y >> 16);
  f[4] = bf2f(v.z & 0xffffu); f[5] = bf2f(v.z >> 16);
  f[6] = bf2f(v.w & 0xffffu); f[7] = bf2f(v.w >> 16);
}

// ---------------- CSR build (rank trick) ----------------
// Pass 1: rank[g] = atomicAdd(cnt[r][dst[g]], 1). After this, cnt = degrees.
__global__ void rank_k(const int* __restrict__ dst, int E, int Nn,
                       int* __restrict__ cnt, int* __restrict__ rank) {
  int base = (blockIdx.x * blockDim.x + threadIdx.x) * 8;
  int r = blockIdx.y;
  if (base >= E) return;
  const int* dr = dst + (size_t)r * E;
  int* cr = cnt + (size_t)r * Nn;
  int* rk = rank + (size_t)r * E;
  if (base + 7 < E) {
    const int4 a = *reinterpret_cast<const int4*>(dr + base);
    const int4 b = *reinterpret_cast<const int4*>(dr + base + 4);
    int4 ra, rb;
    ra.x = atomicAdd(&cr[a.x], 1); ra.y = atomicAdd(&cr[a.y], 1);
    ra.z = atomicAdd(&cr[a.z], 1); ra.w = atomicAdd(&cr[a.w], 1);
    rb.x = atomicAdd(&cr[b.x], 1); rb.y = atomicAdd(&cr[b.y], 1);
    rb.z = atomicAdd(&cr[b.z], 1); rb.w = atomicAdd(&cr[b.w], 1);
    *reinterpret_cast<int4*>(rk + base) = ra;
    *reinterpret_cast<int4*>(rk + base + 4) = rb;
  } else {
    for (int j = 0; j < 8 && base + j < E; j++)
      rk[base + j] = atomicAdd(&cr[dr[base + j]], 1);
  }
}

// Phase A: per-block (1024 elems) exclusive scan of cnt -> rowptr, block sums.
__global__ __launch_bounds__(1024) void scanA_k(const int* __restrict__ degcnt, int M,
                                                int* __restrict__ rowptr,
                                                int* __restrict__ blocksum) {
  __shared__ int sm[1024];
  int t = threadIdx.x;
  int g = blockIdx.x * 1024 + t;
  int v = (g < M) ? degcnt[g] : 0;
  sm[t] = v;
  __syncthreads();
  for (int off = 1; off < 1024; off <<= 1) {
    int u = (t >= off) ? sm[t - off] : 0;
    __syncthreads();
    sm[t] += u;
    __syncthreads();
  }
  if (g < M) rowptr[g] = sm[t] - v;
  if (t == 1023) blocksum[blockIdx.x] = sm[1023];
}

// Phase B: one block scans the block sums (exclusive, in place). nb <= 1024.
__global__ __launch_bounds__(1024) void scanB_k(int* __restrict__ blocksum, int nb) {
  __shared__ int sm[1024];
  int t = threadIdx.x;
  int v = (t < nb) ? blocksum[t] : 0;
  sm[t] = v;
  __syncthreads();
  for (int off = 1; off < 1024; off <<= 1) {
    int u = (t >= off) ? sm[t - off] : 0;
    __syncthreads();
    sm[t] += u;
    __syncthreads();
  }
  if (t < nb) blocksum[t] = sm[t] - v;
}

// Phase C: add block offset; emit final rowptr and invdeg.
__global__ __launch_bounds__(1024) void scanC_k(const int* __restrict__ degcnt, int M,
                                                const int* __restrict__ blocksum,
                                                int* __restrict__ rowptr,
                                                float* __restrict__ invdeg) {
  int g = blockIdx.x * 1024 + threadIdx.x;
  if (g < M) {
    int val = rowptr[g] + blocksum[blockIdx.x];
    int dd = degcnt[g];
    rowptr[g] = val;
    invdeg[g] = 1.0f / (float)(dd > 0 ? dd : 1);
    if (g == M - 1) rowptr[M] = val + dd;
  }
}

// Pass 2: eidx[rowptr[r][dst] + rank] = src. NO atomics.
__global__ void fill_k(const int* __restrict__ src, const int* __restrict__ dst,
                       const int* __restrict__ rank,
                       const int* __restrict__ rowptr, int E, int Nn,
                       int* __restrict__ eidx) {
  int base = (blockIdx.x * blockDim.x + threadIdx.x) * 8;
  int r = blockIdx.y;
  if (base >= E) return;
  const int* dr = dst + (size_t)r * E;
  const int* sr = src + (size_t)r * E;
  const int* rk = rank + (size_t)r * E;
  const int* rp = rowptr + (size_t)r * Nn;
  if (base + 7 < E) {
    const int4 d0 = *reinterpret_cast<const int4*>(dr + base);
    const int4 d1 = *reinterpret_cast<const int4*>(dr + base + 4);
    const int4 s0 = *reinterpret_cast<const int4*>(sr + base);
    const int4 s1 = *reinterpret_cast<const int4*>(sr + base + 4);
    const int4 k0 = *reinterpret_cast<const int4*>(rk + base);
    const int4 k1 = *reinterpret_cast<const int4*>(rk + base + 4);
    eidx[rp[d0.x] + k0.x] = s0.x;
    eidx[rp[d0.y] + k0.y] = s0.y;
    eidx[rp[d0.z] + k0.z] = s0.z;
    eidx[rp[d0.w] + k0.w] = s0.w;
    eidx[rp[d1.x] + k1.x] = s1.x;
    eidx[rp[d1.y] + k1.y] = s1.y;
    eidx[rp[d1.z] + k1.z] = s1.z;
    eidx[rp[d1.w] + k1.w] = s1.w;
  } else {
    for (int j = 0; j < 8 && base + j < E; j++)
      eidx[rp[dr[base + j]] + rk[base + j]] = sr[base + j];
  }
}

// ---------------- prep: f32 -> bf16, weight transpose ----------------
__global__ void f2bf_vec_k(const float* __restrict__ in, ushort_t* __restrict__ out,
                           long n4) {
  long i = (long)blockIdx.x * blockDim.x + threadIdx.x;
  if (i < n4) {
    float4 v = *reinterpret_cast<const float4*>(in + i * 4);
    ushort4 o; o.x = f2bf(v.x); o.y = f2bf(v.y); o.z = f2bf(v.z); o.w = f2bf(v.w);
    *reinterpret_cast<ushort4*>(out + i * 4) = o;
  }
}

// Bt[j][k] = (bf16) w[r][k][c] with j = r*Nd + c.
__global__ void wtrans_k(const float* __restrict__ w, ushort_t* __restrict__ wt,
                         int K, int Nd, int total) {
  int tid = blockIdx.x * blockDim.x + threadIdx.x;
  if (tid < total) {
    int k = tid % K;
    int j = tid / K;
    int c = j % Nd;
    int r = j / Nd;
    wt[(size_t)j * K + k] = f2bf(w[((size_t)r * K + k) * Nd + c]);
  }
}

// ---------------- pull, 256 cols: 2 nodes/wave, 32 lanes x uint4 (16B) -------
__global__ __launch_bounds__(256) void pull_gather256_k(
    const ushort_t* __restrict__ x, int xpitch, int rsub,
    const int* __restrict__ eidx,
    const int* __restrict__ rowptr, const float* __restrict__ invdeg,
    int R, int Nn, ushort_t* __restrict__ out, const float* __restrict__ bias) {
  int wv = (blockIdx.x * blockDim.x + threadIdx.x) >> 6;
  int lane = threadIdx.x & 63;
  int node = (wv << 1) + (lane >> 5);
  if (node >= Nn) return;
  int col8 = (lane & 31) << 3;
  float s[8] = {};
  for (int r = 0; r < R; r++) {
    const int* rp = rowptr + (size_t)r * Nn;   // flat; rp[node+1] valid at boundary
    int sb = rp[node], e = rp[node + 1];
    size_t rb = (size_t)(r * rsub + col8);
    float p[8] = {};
    for (int i = sb; i < e; i += 4) {
      int i1 = i + 1 < e ? i + 1 : i;
      int i2 = i + 2 < e ? i + 2 : i;
      int i3 = i + 3 < e ? i + 3 : i;
      float m1 = i + 1 < e ? 1.f : 0.f;
      float m2 = i + 2 < e ? 1.f : 0.f;
      float m3 = i + 3 < e ? 1.f : 0.f;
      const uint4 v0 = *reinterpret_cast<const uint4*>(x + (size_t)eidx[i]  * xpitch + rb);
      const uint4 v1 = *reinterpret_cast<const uint4*>(x + (size_t)eidx[i1] * xpitch + rb);
      const uint4 v2 = *reinterpret_cast<const uint4*>(x + (size_t)eidx[i2] * xpitch + rb);
      const uint4 v3 = *reinterpret_cast<const uint4*>(x + (size_t)eidx[i3] * xpitch + rb);
      float a0[8], a1[8], a2[8], a3[8];
      u4tof8(v0, a0); u4tof8(v1, a1); u4tof8(v2, a2); u4tof8(v3, a3);
#pragma unroll
      for (int j = 0; j < 8; j++)
        p[j] += (a0[j] + m1 * a1[j]) + (m2 * a2[j] + m3 * a3[j]);
    }
    float w = invdeg[(size_t)r * Nn + node];
#pragma unroll
    for (int j = 0; j < 8; j++) s[j] += p[j] * w;
  }
  const float4 ba = *reinterpret_cast<const float4*>(bias + col8);
  const float4 bb = *reinterpret_cast<const float4*>(bias + col8 + 4);
  s[0] += ba.x; s[1] += ba.y; s[2] += ba.z; s[3] += ba.w;
  s[4] += bb.x; s[5] += bb.y; s[6] += bb.z; s[7] += bb.w;
  short8 ov;
#pragma unroll
  for (int j = 0; j < 8; j++) ov[j] = (short)f2bf(fmaxf(s[j], 0.f));
  *reinterpret_cast<short8*>(out + ((size_t)node << 8) + col8) = ov;
}

// ---------------- output pull, 64 cols: 4 edge slots x 16 lanes x uint2 ------
__global__ __launch_bounds__(256) void pull_out64_k(
    const ushort_t* __restrict__ q, int qpitch,
    const int* __restrict__ eidx,
    const int* __restrict__ rowptr, const float* __restrict__ invdeg,
    int R, int Nn, float* __restrict__ out, const float* __restrict__ bias) {
  int node = (blockIdx.x * blockDim.x + threadIdx.x) >> 6;
  if (node >= Nn) return;
  int lane = threadIdx.x & 63;
  int es = lane >> 4;           // edge slot 0..3
  int c4 = (lane & 15) << 2;    // 4 cols per lane (uint2 = 4 bf16)
  float s[4] = {};
  for (int r = 0; r < R; r++) {
    const int* rp = rowptr + (size_t)r * Nn;
    int sb = rp[node], e = rp[node + 1];
    size_t rb = (size_t)((r << 6) + c4);
    float p[4] = {};
    for (int i = sb + es; i < e; i += 4) {
      const uint2 v = *reinterpret_cast<const uint2*>(q + (size_t)eidx[i] * qpitch + rb);
      p[0] += bf2f(v.x & 0xffffu); p[1] += bf2f(v.x >> 16);
      p[2] += bf2f(v.y & 0xffffu); p[3] += bf2f(v.y >> 16);
    }
    float w = invdeg[(size_t)r * Nn + node];
#pragma unroll
    for (int j = 0; j < 4; j++) s[j] += p[j] * w;
  }
#pragma unroll
  for (int j = 0; j < 4; j++) {
    s[j] += __shfl_xor(s[j], 16, 64);
    s[j] += __shfl_xor(s[j], 32, 64);
  }
  if (es == 0) {
    const float4 bv = *reinterpret_cast<const float4*>(bias + c4);
    float4 o;
    o.x = s[0] + bv.x; o.y = s[1] + bv.y; o.z = s[2] + bv.z; o.w = s[3] + bv.w;
    *reinterpret_cast<float4*>(out + ((size_t)node << 6) + c4) = o;
  }
}

// ---------------- bf16 MFMA GEMM (no bias/relu, bf16 store) ----------------
// 1D grid with bijective XCD-chunked swizzle (m204): consecutive logical tiles
// (which share A row-tiles across col-tiles) land on the same XCD's L2.
template <int FN>
__global__ __launch_bounds__(256) void gemm_mfma_k(
    const ushort_t* __restrict__ A, const ushort_t* __restrict__ Bt,
    ushort_t* __restrict__ Cp, int M, int K, int Nd, int gx) {
  // --- bijective XCD swizzle: hw bid -> logical wgid ---
  int nwg = gridDim.x;
  int orig = blockIdx.x;
  int q8 = nwg >> 3, r8 = nwg & 7;
  int xcd = orig & 7, idx = orig >> 3;
  int wgid = (xcd < r8 ? xcd * (q8 + 1) : r8 * (q8 + 1) + (xcd - r8) * q8) + idx;
  int bx = wgid % gx;
  int by = wgid / gx;

  __shared__ ushort_t Atile[128][72];
  const int tid = threadIdx.x;
  const int lane = tid & 63;
  const int wid = tid >> 6;
  const int wr = wid >> 1;
  const int wc = wid & 1;
  const int rowBase = by * 128;
  const int colBase = bx * (FN * 32);
  const int l15 = lane & 15;
  const int g = lane >> 4;

  f32x4 acc[4][FN] = {};

  const int srow = tid >> 3;
  const int schunk = tid & 7;

  for (int k0 = 0; k0 < K; k0 += 64) {
#pragma unroll
    for (int i = 0; i < 4; i++) {
      int row = srow + i * 32;
      int grow = rowBase + row;
      if (grow >= M) grow = M - 1;  // clamp: affects only unstored C rows
      short8 v = *reinterpret_cast<const short8*>(A + (size_t)grow * K + k0 + schunk * 8);
      *reinterpret_cast<short8*>(&Atile[row][schunk * 8]) = v;
    }
    __syncthreads();
#pragma unroll
    for (int kk = 0; kk < 2; kk++) {
      short8 a[4], b[FN];
#pragma unroll
      for (int m = 0; m < 4; m++)
        a[m] = *reinterpret_cast<const short8*>(&Atile[wr * 64 + m * 16 + l15][kk * 32 + g * 8]);
#pragma unroll
      for (int n = 0; n < FN; n++) {
        int col = colBase + wc * (FN * 16) + n * 16 + l15;
        b[n] = *reinterpret_cast<const short8*>(Bt + (size_t)col * K + k0 + kk * 32 + g * 8);
      }
#pragma unroll
      for (int m = 0; m < 4; m++)
#pragma unroll
        for (int n = 0; n < FN; n++)
          acc[m][n] = __builtin_amdgcn_mfma_f32_16x16x32_bf16(a[m], b[n], acc[m][n], 0, 0, 0);
    }
    __syncthreads();
  }

  // C/D layout: col=lane&15, row=(lane>>4)*4+reg  [guide §3, m89-verified]
#pragma unroll
  for (int n = 0; n < FN; n++) {
    int col = colBase + wc * (FN * 16) + n * 16 + l15;
#pragma unroll
    for (int m = 0; m < 4; m++) {
      int row0 = rowBase + wr * 64 + m * 16 + g * 4;
#pragma unroll
      for (int j = 0; j < 4; j++) {
        int row = row0 + j;
        if (row < M) Cp[(size_t)row * Nd + col] = f2bf(acc[m][n][j]);
      }
    }
  }
}

extern "C" void kernel_launch(void* const* d_in, const int* in_sizes, int n_in,
                              void* d_out, int out_size, void* d_ws, size_t ws_size,
                              hipStream_t stream) {
  const float* embed = (const float*)d_in[0];
  const int* src     = (const int*)d_in[1];
  const int* dst     = (const int*)d_in[2];
  const float* b0    = (const float*)d_in[3];
  const float* w1    = (const float*)d_in[4];
  const float* b1    = (const float*)d_in[5];
  const float* w_out = (const float*)d_in[6];
  const float* b_out = (const float*)d_in[7];
  float* out = (float*)d_out;

  const int D = in_sizes[3];            // 256
  const int C = in_sizes[7];            // 64
  const int N = in_sizes[0] / D;        // 50000
  const int R = in_sizes[4] / (D * D);  // 4
  const int E = in_sizes[1] / R;        // 400000
  const int M = R * N;                  // scan length
  const int N1 = R * D;                 // 1024 gemm1 out cols
  const int N2 = R * C;                 // 256  gemm2 out cols

  char* w = (char*)d_ws;
  size_t off = 0;
  auto carve = [&](size_t bytes) -> void* {
    void* p = w + off;
    off += (bytes + 255) & ~(size_t)255;
    return p;
  };
  ushort_t* ebf  = (ushort_t*)carve((size_t)N * D * 2);       // 25.6 MB (reused as h2)
  ushort_t* h    = (ushort_t*)carve((size_t)N * D * 2);       // 25.6 MB
  ushort_t* t    = (ushort_t*)carve((size_t)N * N1 * 2);      // 102.4 MB (reused as q; rank aliases head)
  ushort_t* w1t  = (ushort_t*)carve((size_t)N1 * D * 2);      // 0.5 MB
  ushort_t* wot  = (ushort_t*)carve((size_t)N2 * D * 2);      // 0.13 MB
  float* invdeg  = (float*)carve((size_t)M * 4);
  int* rowptr    = (int*)carve(((size_t)M + 1) * 4);
  int* degcnt    = (int*)carve((size_t)M * 4);
  int* eidx      = (int*)carve((size_t)R * E * 4);
  int* blocksum  = (int*)carve(1024 * 4);
  ushort_t* h2 = ebf;   // ebf dead after layer-0 pull
  ushort_t* q  = t;     // t dead after layer-1 pull
  int* rank = (int*)t;  // t-space unused until gemm1; rank dead after fill_k
  (void)n_in; (void)out_size; (void)ws_size;

  // --- CSR build: rank pass (atomic, leaves degrees) -> scan -> atomic-free fill ---
  hipMemsetAsync(degcnt, 0, (size_t)M * 4, stream);
  dim3 egrid((E + 2047) / 2048, R);
  rank_k<<<egrid, 256, 0, stream>>>(dst, E, N, degcnt, rank);
  int nblkScan = (M + 1023) / 1024;     // 196 <= 1024
  scanA_k<<<nblkScan, 1024, 0, stream>>>(degcnt, M, rowptr, blocksum);
  scanB_k<<<1, 1024, 0, stream>>>(blocksum, nblkScan);
  scanC_k<<<nblkScan, 1024, 0, stream>>>(degcnt, M, blocksum, rowptr, invdeg);
  fill_k<<<egrid, 256, 0, stream>>>(src, dst, rank, rowptr, E, N, eidx);

  // --- prep: embed->bf16, weights -> [outcol][k] bf16 ---
  long n4 = (long)N * D / 4;
  f2bf_vec_k<<<(int)((n4 + 255) / 256), 256, 0, stream>>>(embed, ebf, n4);
  wtrans_k<<<(N1 * D + 255) / 256, 256, 0, stream>>>(w1, w1t, D, D, N1 * D);
  wtrans_k<<<(N2 * D + 255) / 256, 256, 0, stream>>>(w_out, wot, D, C, N2 * D);

  const int pullBlocks2 = ((N + 1) / 2 * 64 + 255) / 256;  // 2 nodes per wave
  const int pullBlocks1 = (N * 64 + 255) / 256;            // 1 node per wave
  const int rowTiles = (N + 127) / 128;                    // 391

  // --- layer 0: h = relu(b0 + sum_r agg_r(embed)) ---
  pull_gather256_k<<<pullBlocks2, 256, 0, stream>>>(ebf, D, 0, eidx, rowptr, invdeg,
                                                    R, N, h, b0);

  // --- layer 1: t = h @ w1cat; h2 = relu(b1 + sum_r agg_r(t[:,r*256:])) ---
  {
    int gx = N1 / 128;                                     // 8 col tiles
    gemm_mfma_k<4><<<gx * rowTiles, 256, 0, stream>>>(h, w1t, t, N, D, N1, gx);
  }
  pull_gather256_k<<<pullBlocks2, 256, 0, stream>>>(t, N1, D, eidx, rowptr, invdeg,
                                                    R, N, h2, b1);

  // --- layer 2: q = h2 @ wocat; out = b_out + sum_r agg_r(q[:,r*64:]) ---
  {
    int gx = N2 / 128;                                     // 2 col tiles
    gemm_mfma_k<4><<<gx * rowTiles, 256, 0, stream>>>(h2, wot, q, N, D, N2, gx);
  }
  pull_out64_k<<<pullBlocks1, 256, 0, stream>>>(q, N2, eidx, rowptr, invdeg,
                                                R, N, out, b_out);
}